// Round 7
// baseline (250.691 us; speedup 1.0000x reference)
//
#include <hip/hip_runtime.h>
#include <hip/hip_bf16.h>

#define BATCH 4
#define SEQ   2048
#define DM    512
#define NH    8
#define HD    64
#define PART  (BATCH*NH*SEQ*HD)   /* 4,194,304 = M*DM */
#define QSCALE 0.18033688f        /* (1/sqrt(64)) * log2(e) : folded into Q */

typedef unsigned short u16;
typedef unsigned int   u32;
typedef __bf16 bf16x8 __attribute__((ext_vector_type(8)));
typedef float  f32x4  __attribute__((ext_vector_type(4)));

__device__ __forceinline__ u16 f2bf(float f) {
    union { float f; u32 u; } v; v.f = f;
    u32 r = v.u + 0x7fffu + ((v.u >> 16) & 1u);   // RNE
    return (u16)(r >> 16);
}

// async global->LDS, 16B per lane; LDS dest = uniform base + lane*16
__device__ __forceinline__ void glds16(const u16* g, u16* lds) {
    __builtin_amdgcn_global_load_lds(
        (const __attribute__((address_space(1))) void*)g,
        (__attribute__((address_space(3))) void*)lds, 16, 0, 0);
}

// ---------------------------------------------------------------------------
// prep: z=0 -> f32->bf16 convert of x (512 blocks, grid-stride)
//       z=1 -> transpose w_qkv (192 blocks)   z=2 -> transpose w_out (64)
// ---------------------------------------------------------------------------
__global__ __launch_bounds__(256) void prep_k(
    const float* __restrict__ x, u16* __restrict__ xb,
    const float* __restrict__ w_qkv, u16* __restrict__ t_qkv,
    const float* __restrict__ w_out, u16* __restrict__ t_out)
{
    __shared__ u16 Ts[64][72];
    const int z = blockIdx.z, bx = blockIdx.x, t = threadIdx.x;

    if (z == 0) {
        const int n8 = PART / 8;
        for (int i = bx * 256 + t; i < n8; i += 512 * 256) {
            float4 a = *(const float4*)(x + (size_t)i * 8);
            float4 b = *(const float4*)(x + (size_t)i * 8 + 4);
            union { uint4 v; u16 s[8]; } o;
            o.s[0] = f2bf(a.x); o.s[1] = f2bf(a.y);
            o.s[2] = f2bf(a.z); o.s[3] = f2bf(a.w);
            o.s[4] = f2bf(b.x); o.s[5] = f2bf(b.y);
            o.s[6] = f2bf(b.z); o.s[7] = f2bf(b.w);
            *(uint4*)(xb + (size_t)i * 8) = o.v;
        }
        return;
    }
    const int N = (z == 1) ? 3 * DM : DM;
    const int ntiles = N / 64;
    if (bx >= ntiles * 8) return;
    const float* W = (z == 1) ? w_qkv : w_out;
    u16* Wt = (z == 1) ? t_qkv : t_out;
    const int n0 = (bx % ntiles) * 64, k0 = (bx / ntiles) * 64;

    #pragma unroll
    for (int l = 0; l < 4; ++l) {
        int idx = l * 1024 + t * 4;
        int r = idx >> 6, c = idx & 63;
        float4 v = *(const float4*)(W + (size_t)(k0 + r) * N + n0 + c);
        Ts[c + 0][r] = f2bf(v.x);
        Ts[c + 1][r] = f2bf(v.y);
        Ts[c + 2][r] = f2bf(v.z);
        Ts[c + 3][r] = f2bf(v.w);
    }
    __syncthreads();
    #pragma unroll
    for (int l = 0; l < 2; ++l) {
        int idx = l * 256 + t;
        int row = idx >> 3, ch = idx & 7;
        *(uint4*)(Wt + (size_t)(n0 + row) * DM + k0 + ch * 8) =
            *(const uint4*)(&Ts[row][ch * 8]);
    }
}

// ---------------------------------------------------------------------------
// GEMM: C(M,N) = A(M,K)bf16 @ Bt(N,K)^T bf16 + bias(N)f32.
// Double-buffered LDS, one barrier per K-step.
// MODE 0: scatter into ws: Q (prescaled) | K as (B,H,S,HD); V as (B,H,HD,S).
// MODE 1: row-major f32 store to d_out.
// ---------------------------------------------------------------------------
template<int MODE>
__global__ __launch_bounds__(256) void gemm_k(
    const u16* __restrict__ A, const u16* __restrict__ Bt,
    const float* __restrict__ bias, void* __restrict__ outv,
    int M, int N, int K)
{
    __shared__ __align__(16) u16 As[2][128 * 32];
    __shared__ __align__(16) u16 Bs[2][128 * 32];

    const int tid  = threadIdx.x;
    const int bm0  = blockIdx.x * 128;
    const int bn0  = blockIdx.y * 128;
    const int wave = tid >> 6, lane = tid & 63;
    const int l16  = lane & 15, quad = lane >> 4;
    const int wr   = (wave & 1) * 64;
    const int wc   = (wave >> 1) * 64;

    const int srow = (lane >> 2);            // 0..15
    const int scol = (lane & 3) * 8;         // 0,8,16,24
    const u16* Ag = A + (size_t)(bm0 + wave * 32 + srow) * K + scol;
    const u16* Bg = Bt + (size_t)(bn0 + wave * 32 + srow) * K + scol;
    const int wofs = (wave * 32) * 32;

    f32x4 acc[4][4];
    #pragma unroll
    for (int i = 0; i < 4; ++i)
        #pragma unroll
        for (int j = 0; j < 4; ++j)
            acc[i][j] = (f32x4){0.f, 0.f, 0.f, 0.f};

    glds16(Ag,                  &As[0][wofs]);
    glds16(Ag + (size_t)16 * K, &As[0][wofs + 16 * 32]);
    glds16(Bg,                  &Bs[0][wofs]);
    glds16(Bg + (size_t)16 * K, &Bs[0][wofs + 16 * 32]);
    __syncthreads();

    const int NIT = K >> 5;
    for (int it = 0; it < NIT; ++it) {
        const int cur = it & 1;
        if (it + 1 < NIT) {
            const int nx = cur ^ 1;
            const int k0 = (it + 1) << 5;
            glds16(Ag + k0,                  &As[nx][wofs]);
            glds16(Ag + k0 + (size_t)16 * K, &As[nx][wofs + 16 * 32]);
            glds16(Bg + k0,                  &Bs[nx][wofs]);
            glds16(Bg + k0 + (size_t)16 * K, &Bs[nx][wofs + 16 * 32]);
        }

        bf16x8 af[4], bfr[4];
        #pragma unroll
        for (int mi = 0; mi < 4; ++mi)
            af[mi] = *(const bf16x8*)(&As[cur][(wr + mi * 16 + l16) * 32 + quad * 8]);
        #pragma unroll
        for (int ni = 0; ni < 4; ++ni)
            bfr[ni] = *(const bf16x8*)(&Bs[cur][(wc + ni * 16 + l16) * 32 + quad * 8]);
        #pragma unroll
        for (int mi = 0; mi < 4; ++mi)
            #pragma unroll
            for (int ni = 0; ni < 4; ++ni)
                acc[mi][ni] = __builtin_amdgcn_mfma_f32_16x16x32_bf16(
                    af[mi], bfr[ni], acc[mi][ni], 0, 0, 0);
        __syncthreads();
    }

    #pragma unroll
    for (int mi = 0; mi < 4; ++mi) {
        #pragma unroll
        for (int ni = 0; ni < 4; ++ni) {
            int col = bn0 + wc + ni * 16 + l16;
            float bv = bias[col];
            int row0 = bm0 + wr + mi * 16 + quad * 4;
            float v[4];
            #pragma unroll
            for (int reg = 0; reg < 4; ++reg) v[reg] = acc[mi][ni][reg] + bv;

            if (MODE == 1) {
                #pragma unroll
                for (int reg = 0; reg < 4; ++reg)
                    ((float*)outv)[(size_t)(row0 + reg) * N + col] = v[reg];
            } else {
                u16* ws = (u16*)outv;
                int part = col >> 9, wi = col & 511;
                int h = wi >> 6, e = wi & 63;
                int b = row0 >> 11, s0 = row0 & 2047;
                if (part == 2) {
                    union { u16 q[4]; uint2 u; } pk;
                    #pragma unroll
                    for (int reg = 0; reg < 4; ++reg) pk.q[reg] = f2bf(v[reg]);
                    *(uint2*)(ws + (size_t)2 * PART +
                              ((size_t)(b * NH + h) * HD + e) * SEQ + s0) = pk.u;
                } else {
                    float scl = (part == 0) ? QSCALE : 1.0f;
                    #pragma unroll
                    for (int reg = 0; reg < 4; ++reg)
                        ws[(size_t)part * PART +
                           ((size_t)(b * NH + h) * SEQ + s0 + reg) * HD + e] =
                            f2bf(v[reg] * scl);
                }
            }
        }
    }
}

// ---------------------------------------------------------------------------
// Causal flash attention, streaming softmax (exp2; scale folded into Q).
// Q,K: (B,H,S,HD) bf16. Vt: (B,H,HD,S) bf16. Out: (B,S,H,HD) bf16.
// BARRIER-FREE k-loop: K/V fragments are loaded straight from global memory
// into VGPRs (both are 16B-contiguous for the MFMA B-operand layout); K frags
// are register-double-buffered one iteration ahead. Ps (P tile) is
// wave-private, ordered by lgkmcnt only. L2 locality: grid x=bh so all 16
// q-blocks of a bh share an XCD (round-6: FETCH 55->12 MB).
// LPT pairing: qb = y<8 ? 15-y : y-8 (CU's two blocks sum to 36 iters).
// ---------------------------------------------------------------------------
__global__ __launch_bounds__(256, 2) void attn_k(
    const u16* __restrict__ Q, const u16* __restrict__ K,
    const u16* __restrict__ Vt, u16* __restrict__ O)
{
    __shared__ __align__(16) u16 Ps[128][72];   // Q stage, then P (wave-private)

    const int bh = blockIdx.x;
    const int yy = blockIdx.y;
    const int qb = (yy < 8) ? (15 - yy) : (yy - 8);
    const int tid = threadIdx.x, wave = tid >> 6, lane = tid & 63;
    const int l16 = lane & 15, quad = lane >> 4;
    const size_t baseK = (size_t)bh * SEQ * HD;
    const size_t baseV = (size_t)bh * HD * SEQ;
    const size_t baseQ = baseK + (size_t)qb * 128 * HD;

    // ---- stage Q (128x64) into Ps ----
    #pragma unroll
    for (int r = 0; r < 4; ++r) {
        int chunk = r * 256 + tid;
        int row = chunk >> 3, c8 = (chunk & 7) << 3;
        *(uint4*)(&Ps[row][c8]) = *(const uint4*)(Q + baseQ + row * 64 + c8);
    }
    __syncthreads();

    bf16x8 qf[2][2];
    #pragma unroll
    for (int rf = 0; rf < 2; ++rf)
        #pragma unroll
        for (int d0 = 0; d0 < 2; ++d0)
            qf[rf][d0] = *(const bf16x8*)(&Ps[rf * 64 + wave * 16 + l16]
                                            [d0 * 32 + quad * 8]);
    __syncthreads();   // all qf reads done before any wave overwrites Ps with P

    const u16* Kb = K + baseK;
    const u16* Vb = Vt + baseV;

    // K-fragment register double-buffer, prefetch kt=0
    bf16x8 kf[2][2][4];
    #pragma unroll
    for (int d0 = 0; d0 < 2; ++d0)
        #pragma unroll
        for (int nt = 0; nt < 4; ++nt)
            kf[0][d0][nt] = *(const bf16x8*)
                (Kb + (size_t)(nt * 16 + l16) * 64 + d0 * 32 + quad * 8);

    float l_part[2][4];
    f32x4 o_acc[2][4];
    #pragma unroll
    for (int rf = 0; rf < 2; ++rf)
        #pragma unroll
        for (int i = 0; i < 4; ++i) {
            l_part[rf][i] = 0.f;
            o_acc[rf][i] = (f32x4){0.f, 0.f, 0.f, 0.f};
        }

    const int last = 2 * qb + 1;
    const int row64 = wave * 16 + quad * 4;

    for (int kt = 0; kt <= last; ++kt) {
        const int cur = kt & 1;

        // V frags for THIS iter (used after QK+exp: latency hidden)
        bf16x8 vf[2][4];
        #pragma unroll
        for (int k0 = 0; k0 < 2; ++k0)
            #pragma unroll
            for (int dt = 0; dt < 4; ++dt)
                vf[k0][dt] = *(const bf16x8*)
                    (Vb + (size_t)(dt * 16 + l16) * SEQ +
                     kt * 64 + k0 * 32 + quad * 8);

        // prefetch K frags for NEXT iter
        if (kt < last) {
            #pragma unroll
            for (int d0 = 0; d0 < 2; ++d0)
                #pragma unroll
                for (int nt = 0; nt < 4; ++nt)
                    kf[cur ^ 1][d0][nt] = *(const bf16x8*)
                        (Kb + (size_t)((kt + 1) * 64 + nt * 16 + l16) * 64 +
                         d0 * 32 + quad * 8);
        }

        #pragma unroll
        for (int rf = 0; rf < 2; ++rf) {
            if (kt == last && rf == 0) continue;     // fully-masked half
            f32x4 s[4];
            #pragma unroll
            for (int nt = 0; nt < 4; ++nt) s[nt] = (f32x4){0.f, 0.f, 0.f, 0.f};
            #pragma unroll
            for (int d0 = 0; d0 < 2; ++d0)
                #pragma unroll
                for (int nt = 0; nt < 4; ++nt)
                    s[nt] = __builtin_amdgcn_mfma_f32_16x16x32_bf16(
                        qf[rf][d0], kf[cur][d0][nt], s[nt], 0, 0, 0);

            const bool diag = (kt == 2 * qb + rf);
            #pragma unroll
            for (int nt = 0; nt < 4; ++nt) {
                int cl = nt * 16 + l16;
                float p[4];
                #pragma unroll
                for (int reg = 0; reg < 4; ++reg) {
                    p[reg] = __builtin_amdgcn_exp2f(s[nt][reg]);
                    if (diag && cl > row64 + reg) p[reg] = 0.f;
                    l_part[rf][reg] += p[reg];
                }
                union { __hip_bfloat162 h; u16 s2[2]; } pk01, pk23;
                pk01.h = __float22bfloat162_rn(float2{p[0], p[1]});
                pk23.h = __float22bfloat162_rn(float2{p[2], p[3]});
                Ps[rf * 64 + row64 + 0][cl] = pk01.s2[0];
                Ps[rf * 64 + row64 + 1][cl] = pk01.s2[1];
                Ps[rf * 64 + row64 + 2][cl] = pk23.s2[0];
                Ps[rf * 64 + row64 + 3][cl] = pk23.s2[1];
            }

            // PV: Ps rows wave-private; lgkmcnt orders write->read
            #pragma unroll
            for (int k0 = 0; k0 < 2; ++k0) {
                bf16x8 ap = *(const bf16x8*)
                    (&Ps[rf * 64 + wave * 16 + l16][k0 * 32 + quad * 8]);
                #pragma unroll
                for (int dt = 0; dt < 4; ++dt)
                    o_acc[rf][dt] = __builtin_amdgcn_mfma_f32_16x16x32_bf16(
                        ap, vf[k0][dt], o_acc[rf][dt], 0, 0, 0);
            }
        }
    }

    // ---- reduce l across the 16 lanes sharing each q-row; store O ----
    const int b = bh >> 3, h = bh & 7;
    #pragma unroll
    for (int rf = 0; rf < 2; ++rf) {
        float l_i[4];
        #pragma unroll
        for (int reg = 0; reg < 4; ++reg) {
            float l = l_part[rf][reg];
            #pragma unroll
            for (int off = 1; off < 16; off <<= 1)
                l += __shfl_xor(l, off);
            l_i[reg] = l;
        }
        #pragma unroll
        for (int dt = 0; dt < 4; ++dt) {
            #pragma unroll
            for (int reg = 0; reg < 4; ++reg) {
                int srow = qb * 128 + rf * 64 + row64 + reg;
                float v = o_acc[rf][dt][reg] / l_i[reg];
                size_t idx = (((size_t)(b * SEQ + srow)) * NH + h) * HD
                             + dt * 16 + l16;
                O[idx] = f2bf(v);
            }
        }
    }
}

extern "C" void kernel_launch(void* const* d_in, const int* in_sizes, int n_in,
                              void* d_out, int out_size, void* d_ws, size_t ws_size,
                              hipStream_t stream) {
    const float* x     = (const float*)d_in[0];
    const float* w_qkv = (const float*)d_in[1];
    const float* b_qkv = (const float*)d_in[2];
    const float* w_out = (const float*)d_in[3];
    const float* b_out = (const float*)d_in[4];

    u16* qkv    = (u16*)d_ws;                       // Q | K | V^T, each PART
    u16* attn   = qkv + (size_t)3 * PART;           // PART bf16 (B,S,H,HD)
    u16* xb     = attn + (size_t)PART;              // PART bf16 (x converted)
    u16* wt_qkv = xb + (size_t)PART;                // 1536*512 bf16
    u16* wt_out = wt_qkv + (size_t)(3 * DM) * DM;   // 512*512 bf16

    const int M = BATCH * SEQ;                      // 8192

    prep_k<<<dim3(512, 1, 3), 256, 0, stream>>>(x, xb, w_qkv, wt_qkv,
                                                w_out, wt_out);

    dim3 g1(M / 128, (3 * DM) / 128);               // 64 x 12
    gemm_k<0><<<g1, 256, 0, stream>>>(xb, wt_qkv, b_qkv, qkv, M, 3 * DM, DM);

    dim3 g2(BATCH * NH, 16);                        // bh x ypair
    attn_k<<<g2, 256, 0, stream>>>(qkv, qkv + PART, qkv + 2 * (size_t)PART, attn);

    dim3 g3(M / 128, DM / 128);                     // 64 x 4
    gemm_k<1><<<g3, 256, 0, stream>>>(attn, wt_out, b_out, (float*)d_out, M, DM, DM);
}

// Round 8
// 182.013 us; speedup vs baseline: 1.3773x; 1.3773x over previous
//
#include <hip/hip_runtime.h>
#include <hip/hip_bf16.h>

#define BATCH 4
#define SEQ   2048
#define DM    512
#define NH    8
#define HD    64
#define PART  (BATCH*NH*SEQ*HD)   /* 4,194,304 = M*DM */
#define QSCALE 0.18033688f        /* (1/sqrt(64)) * log2(e) : folded into Q */

typedef unsigned short u16;
typedef unsigned int   u32;
typedef __bf16 bf16x8 __attribute__((ext_vector_type(8)));
typedef float  f32x4  __attribute__((ext_vector_type(4)));

__device__ __forceinline__ u16 f2bf(float f) {
    union { float f; u32 u; } v; v.f = f;
    u32 r = v.u + 0x7fffu + ((v.u >> 16) & 1u);   // RNE
    return (u16)(r >> 16);
}

// async global->LDS, 16B per lane; LDS dest = uniform base + lane*16
__device__ __forceinline__ void glds16(const u16* g, u16* lds) {
    __builtin_amdgcn_global_load_lds(
        (const __attribute__((address_space(1))) void*)g,
        (__attribute__((address_space(3))) void*)lds, 16, 0, 0);
}

// ---------------------------------------------------------------------------
// prep: z=0 -> f32->bf16 convert of x (512 blocks, grid-stride)
//       z=1 -> transpose w_qkv (192 blocks)   z=2 -> transpose w_out (64)
// ---------------------------------------------------------------------------
__global__ __launch_bounds__(256) void prep_k(
    const float* __restrict__ x, u16* __restrict__ xb,
    const float* __restrict__ w_qkv, u16* __restrict__ t_qkv,
    const float* __restrict__ w_out, u16* __restrict__ t_out)
{
    __shared__ u16 Ts[64][72];
    const int z = blockIdx.z, bx = blockIdx.x, t = threadIdx.x;

    if (z == 0) {
        const int n8 = PART / 8;
        for (int i = bx * 256 + t; i < n8; i += 512 * 256) {
            float4 a = *(const float4*)(x + (size_t)i * 8);
            float4 b = *(const float4*)(x + (size_t)i * 8 + 4);
            union { uint4 v; u16 s[8]; } o;
            o.s[0] = f2bf(a.x); o.s[1] = f2bf(a.y);
            o.s[2] = f2bf(a.z); o.s[3] = f2bf(a.w);
            o.s[4] = f2bf(b.x); o.s[5] = f2bf(b.y);
            o.s[6] = f2bf(b.z); o.s[7] = f2bf(b.w);
            *(uint4*)(xb + (size_t)i * 8) = o.v;
        }
        return;
    }
    const int N = (z == 1) ? 3 * DM : DM;
    const int ntiles = N / 64;
    if (bx >= ntiles * 8) return;
    const float* W = (z == 1) ? w_qkv : w_out;
    u16* Wt = (z == 1) ? t_qkv : t_out;
    const int n0 = (bx % ntiles) * 64, k0 = (bx / ntiles) * 64;

    #pragma unroll
    for (int l = 0; l < 4; ++l) {
        int idx = l * 1024 + t * 4;
        int r = idx >> 6, c = idx & 63;
        float4 v = *(const float4*)(W + (size_t)(k0 + r) * N + n0 + c);
        Ts[c + 0][r] = f2bf(v.x);
        Ts[c + 1][r] = f2bf(v.y);
        Ts[c + 2][r] = f2bf(v.z);
        Ts[c + 3][r] = f2bf(v.w);
    }
    __syncthreads();
    #pragma unroll
    for (int l = 0; l < 2; ++l) {
        int idx = l * 256 + t;
        int row = idx >> 3, ch = idx & 7;
        *(uint4*)(Wt + (size_t)(n0 + row) * DM + k0 + ch * 8) =
            *(const uint4*)(&Ts[row][ch * 8]);
    }
}

// ---------------------------------------------------------------------------
// GEMM: C(M,N) = A(M,K)bf16 @ Bt(N,K)^T bf16 + bias(N)f32.
// Double-buffered LDS, one barrier per K-step.
// MODE 0: scatter into ws: Q (prescaled) | K as (B,H,S,HD); V as (B,H,HD,S).
// MODE 1: row-major f32 store to d_out.
// ---------------------------------------------------------------------------
template<int MODE>
__global__ __launch_bounds__(256) void gemm_k(
    const u16* __restrict__ A, const u16* __restrict__ Bt,
    const float* __restrict__ bias, void* __restrict__ outv,
    int M, int N, int K)
{
    __shared__ __align__(16) u16 As[2][128 * 32];
    __shared__ __align__(16) u16 Bs[2][128 * 32];

    const int tid  = threadIdx.x;
    const int bm0  = blockIdx.x * 128;
    const int bn0  = blockIdx.y * 128;
    const int wave = tid >> 6, lane = tid & 63;
    const int l16  = lane & 15, quad = lane >> 4;
    const int wr   = (wave & 1) * 64;
    const int wc   = (wave >> 1) * 64;

    const int srow = (lane >> 2);            // 0..15
    const int scol = (lane & 3) * 8;         // 0,8,16,24
    const u16* Ag = A + (size_t)(bm0 + wave * 32 + srow) * K + scol;
    const u16* Bg = Bt + (size_t)(bn0 + wave * 32 + srow) * K + scol;
    const int wofs = (wave * 32) * 32;

    f32x4 acc[4][4];
    #pragma unroll
    for (int i = 0; i < 4; ++i)
        #pragma unroll
        for (int j = 0; j < 4; ++j)
            acc[i][j] = (f32x4){0.f, 0.f, 0.f, 0.f};

    glds16(Ag,                  &As[0][wofs]);
    glds16(Ag + (size_t)16 * K, &As[0][wofs + 16 * 32]);
    glds16(Bg,                  &Bs[0][wofs]);
    glds16(Bg + (size_t)16 * K, &Bs[0][wofs + 16 * 32]);
    __syncthreads();

    const int NIT = K >> 5;
    for (int it = 0; it < NIT; ++it) {
        const int cur = it & 1;
        if (it + 1 < NIT) {
            const int nx = cur ^ 1;
            const int k0 = (it + 1) << 5;
            glds16(Ag + k0,                  &As[nx][wofs]);
            glds16(Ag + k0 + (size_t)16 * K, &As[nx][wofs + 16 * 32]);
            glds16(Bg + k0,                  &Bs[nx][wofs]);
            glds16(Bg + k0 + (size_t)16 * K, &Bs[nx][wofs + 16 * 32]);
        }

        bf16x8 af[4], bfr[4];
        #pragma unroll
        for (int mi = 0; mi < 4; ++mi)
            af[mi] = *(const bf16x8*)(&As[cur][(wr + mi * 16 + l16) * 32 + quad * 8]);
        #pragma unroll
        for (int ni = 0; ni < 4; ++ni)
            bfr[ni] = *(const bf16x8*)(&Bs[cur][(wc + ni * 16 + l16) * 32 + quad * 8]);
        #pragma unroll
        for (int mi = 0; mi < 4; ++mi)
            #pragma unroll
            for (int ni = 0; ni < 4; ++ni)
                acc[mi][ni] = __builtin_amdgcn_mfma_f32_16x16x32_bf16(
                    af[mi], bfr[ni], acc[mi][ni], 0, 0, 0);
        __syncthreads();
    }

    #pragma unroll
    for (int mi = 0; mi < 4; ++mi) {
        #pragma unroll
        for (int ni = 0; ni < 4; ++ni) {
            int col = bn0 + wc + ni * 16 + l16;
            float bv = bias[col];
            int row0 = bm0 + wr + mi * 16 + quad * 4;
            float v[4];
            #pragma unroll
            for (int reg = 0; reg < 4; ++reg) v[reg] = acc[mi][ni][reg] + bv;

            if (MODE == 1) {
                #pragma unroll
                for (int reg = 0; reg < 4; ++reg)
                    ((float*)outv)[(size_t)(row0 + reg) * N + col] = v[reg];
            } else {
                u16* ws = (u16*)outv;
                int part = col >> 9, wi = col & 511;
                int h = wi >> 6, e = wi & 63;
                int b = row0 >> 11, s0 = row0 & 2047;
                if (part == 2) {
                    union { u16 q[4]; uint2 u; } pk;
                    #pragma unroll
                    for (int reg = 0; reg < 4; ++reg) pk.q[reg] = f2bf(v[reg]);
                    *(uint2*)(ws + (size_t)2 * PART +
                              ((size_t)(b * NH + h) * HD + e) * SEQ + s0) = pk.u;
                } else {
                    float scl = (part == 0) ? QSCALE : 1.0f;
                    #pragma unroll
                    for (int reg = 0; reg < 4; ++reg)
                        ws[(size_t)part * PART +
                           ((size_t)(b * NH + h) * SEQ + s0 + reg) * HD + e] =
                            f2bf(v[reg] * scl);
                }
            }
        }
    }
}

// ---------------------------------------------------------------------------
// attention k-tile step: QK^T (MFMA) -> exp2 -> P to LDS -> PV (MFMA).
// kf passed by reference with COMPILE-TIME indexed access only (no dynamic
// register-array indexing -> no scratch spill; round-7 lesson).
// ---------------------------------------------------------------------------
__device__ __forceinline__ void attn_step(
    int kt, int last, int qb, int row64, int l16, int quad, int wave,
    const u16* __restrict__ Vb, const bf16x8 (&kf)[2][4],
    const bf16x8 (&qf)[2][2], float (&l_part)[2][4], f32x4 (&o_acc)[2][4],
    u16 (*Ps)[72])
{
    // V frags for this iter (issued first: global latency hidden behind QK)
    bf16x8 vf[2][4];
    #pragma unroll
    for (int k0 = 0; k0 < 2; ++k0)
        #pragma unroll
        for (int dt = 0; dt < 4; ++dt)
            vf[k0][dt] = *(const bf16x8*)
                (Vb + (size_t)(dt * 16 + l16) * SEQ +
                 kt * 64 + k0 * 32 + quad * 8);

    #pragma unroll
    for (int rf = 0; rf < 2; ++rf) {
        if (kt == last && rf == 0) continue;     // fully-masked half
        f32x4 s[4];
        #pragma unroll
        for (int nt = 0; nt < 4; ++nt) s[nt] = (f32x4){0.f, 0.f, 0.f, 0.f};
        #pragma unroll
        for (int d0 = 0; d0 < 2; ++d0)
            #pragma unroll
            for (int nt = 0; nt < 4; ++nt)
                s[nt] = __builtin_amdgcn_mfma_f32_16x16x32_bf16(
                    qf[rf][d0], kf[d0][nt], s[nt], 0, 0, 0);

        const bool diag = (kt == 2 * qb + rf);
        #pragma unroll
        for (int nt = 0; nt < 4; ++nt) {
            int cl = nt * 16 + l16;
            float p[4];
            #pragma unroll
            for (int reg = 0; reg < 4; ++reg) {
                p[reg] = __builtin_amdgcn_exp2f(s[nt][reg]);
                if (diag && cl > row64 + reg) p[reg] = 0.f;
                l_part[rf][reg] += p[reg];
            }
            union { __hip_bfloat162 h; u16 s2[2]; } pk01, pk23;
            pk01.h = __float22bfloat162_rn(float2{p[0], p[1]});
            pk23.h = __float22bfloat162_rn(float2{p[2], p[3]});
            Ps[rf * 64 + row64 + 0][cl] = pk01.s2[0];
            Ps[rf * 64 + row64 + 1][cl] = pk01.s2[1];
            Ps[rf * 64 + row64 + 2][cl] = pk23.s2[0];
            Ps[rf * 64 + row64 + 3][cl] = pk23.s2[1];
        }

        // PV: Ps rows wave-private; lgkmcnt orders write->read
        #pragma unroll
        for (int k0 = 0; k0 < 2; ++k0) {
            bf16x8 ap = *(const bf16x8*)
                (&Ps[rf * 64 + wave * 16 + l16][k0 * 32 + quad * 8]);
            #pragma unroll
            for (int dt = 0; dt < 4; ++dt)
                o_acc[rf][dt] = __builtin_amdgcn_mfma_f32_16x16x32_bf16(
                    ap, vf[k0][dt], o_acc[rf][dt], 0, 0, 0);
        }
    }
}

// ---------------------------------------------------------------------------
// Causal flash attention, streaming softmax (exp2; scale folded into Q).
// Q,K: (B,H,S,HD) bf16. Vt: (B,H,HD,S) bf16. Out: (B,S,H,HD) bf16.
// Barrier-free k-loop, K/V direct global->VGPR. K frags double-buffered in
// TWO NAMED buffers via unroll-by-2 (trip count 2qb+2 is even) so all
// register indices are compile-time. Grid x=bh keeps a bh's 16 q-blocks on
// one XCD (L2-local); LPT pairing qb = y<8 ? 15-y : y-8.
// ---------------------------------------------------------------------------
__global__ __launch_bounds__(256, 2) void attn_k(
    const u16* __restrict__ Q, const u16* __restrict__ K,
    const u16* __restrict__ Vt, u16* __restrict__ O)
{
    __shared__ __align__(16) u16 Ps[128][72];   // Q stage, then P (wave-private)

    const int bh = blockIdx.x;
    const int yy = blockIdx.y;
    const int qb = (yy < 8) ? (15 - yy) : (yy - 8);
    const int tid = threadIdx.x, wave = tid >> 6, lane = tid & 63;
    const int l16 = lane & 15, quad = lane >> 4;
    const size_t baseK = (size_t)bh * SEQ * HD;
    const size_t baseV = (size_t)bh * HD * SEQ;
    const size_t baseQ = baseK + (size_t)qb * 128 * HD;

    // ---- stage Q (128x64) into Ps ----
    #pragma unroll
    for (int r = 0; r < 4; ++r) {
        int chunk = r * 256 + tid;
        int row = chunk >> 3, c8 = (chunk & 7) << 3;
        *(uint4*)(&Ps[row][c8]) = *(const uint4*)(Q + baseQ + row * 64 + c8);
    }
    __syncthreads();

    bf16x8 qf[2][2];
    #pragma unroll
    for (int rf = 0; rf < 2; ++rf)
        #pragma unroll
        for (int d0 = 0; d0 < 2; ++d0)
            qf[rf][d0] = *(const bf16x8*)(&Ps[rf * 64 + wave * 16 + l16]
                                            [d0 * 32 + quad * 8]);
    __syncthreads();   // all qf reads done before Ps is overwritten with P

    const u16* Kb = K + baseK;
    const u16* Vb = Vt + baseV;

    bf16x8 kfA[2][4], kfB[2][4];
    #pragma unroll
    for (int d0 = 0; d0 < 2; ++d0)
        #pragma unroll
        for (int nt = 0; nt < 4; ++nt)
            kfA[d0][nt] = *(const bf16x8*)
                (Kb + (size_t)(nt * 16 + l16) * 64 + d0 * 32 + quad * 8);

    float l_part[2][4];
    f32x4 o_acc[2][4];
    #pragma unroll
    for (int rf = 0; rf < 2; ++rf)
        #pragma unroll
        for (int i = 0; i < 4; ++i) {
            l_part[rf][i] = 0.f;
            o_acc[rf][i] = (f32x4){0.f, 0.f, 0.f, 0.f};
        }

    const int last = 2 * qb + 1;
    const int row64 = wave * 16 + quad * 4;

    for (int kt = 0; kt <= last; kt += 2) {
        // even step: prefetch kfB for kt+1 (always exists: last is odd)
        #pragma unroll
        for (int d0 = 0; d0 < 2; ++d0)
            #pragma unroll
            for (int nt = 0; nt < 4; ++nt)
                kfB[d0][nt] = *(const bf16x8*)
                    (Kb + (size_t)((kt + 1) * 64 + nt * 16 + l16) * 64 +
                     d0 * 32 + quad * 8);
        attn_step(kt, last, qb, row64, l16, quad, wave,
                  Vb, kfA, qf, l_part, o_acc, Ps);

        // odd step: prefetch kfA for kt+2 if it exists
        if (kt + 1 < last) {
            #pragma unroll
            for (int d0 = 0; d0 < 2; ++d0)
                #pragma unroll
                for (int nt = 0; nt < 4; ++nt)
                    kfA[d0][nt] = *(const bf16x8*)
                        (Kb + (size_t)((kt + 2) * 64 + nt * 16 + l16) * 64 +
                         d0 * 32 + quad * 8);
        }
        attn_step(kt + 1, last, qb, row64, l16, quad, wave,
                  Vb, kfB, qf, l_part, o_acc, Ps);
    }

    // ---- reduce l across the 16 lanes sharing each q-row; store O ----
    const int b = bh >> 3, h = bh & 7;
    #pragma unroll
    for (int rf = 0; rf < 2; ++rf) {
        float l_i[4];
        #pragma unroll
        for (int reg = 0; reg < 4; ++reg) {
            float l = l_part[rf][reg];
            #pragma unroll
            for (int off = 1; off < 16; off <<= 1)
                l += __shfl_xor(l, off);
            l_i[reg] = l;
        }
        #pragma unroll
        for (int dt = 0; dt < 4; ++dt) {
            #pragma unroll
            for (int reg = 0; reg < 4; ++reg) {
                int srow = qb * 128 + rf * 64 + row64 + reg;
                float v = o_acc[rf][dt][reg] / l_i[reg];
                size_t idx = (((size_t)(b * SEQ + srow)) * NH + h) * HD
                             + dt * 16 + l16;
                O[idx] = f2bf(v);
            }
        }
    }
}

extern "C" void kernel_launch(void* const* d_in, const int* in_sizes, int n_in,
                              void* d_out, int out_size, void* d_ws, size_t ws_size,
                              hipStream_t stream) {
    const float* x     = (const float*)d_in[0];
    const float* w_qkv = (const float*)d_in[1];
    const float* b_qkv = (const float*)d_in[2];
    const float* w_out = (const float*)d_in[3];
    const float* b_out = (const float*)d_in[4];

    u16* qkv    = (u16*)d_ws;                       // Q | K | V^T, each PART
    u16* attn   = qkv + (size_t)3 * PART;           // PART bf16 (B,S,H,HD)
    u16* xb     = attn + (size_t)PART;              // PART bf16 (x converted)
    u16* wt_qkv = xb + (size_t)PART;                // 1536*512 bf16
    u16* wt_out = wt_qkv + (size_t)(3 * DM) * DM;   // 512*512 bf16

    const int M = BATCH * SEQ;                      // 8192

    prep_k<<<dim3(512, 1, 3), 256, 0, stream>>>(x, xb, w_qkv, wt_qkv,
                                                w_out, wt_out);

    dim3 g1(M / 128, (3 * DM) / 128);               // 64 x 12
    gemm_k<0><<<g1, 256, 0, stream>>>(xb, wt_qkv, b_qkv, qkv, M, 3 * DM, DM);

    dim3 g2(BATCH * NH, 16);                        // bh x ypair
    attn_k<<<g2, 256, 0, stream>>>(qkv, qkv + PART, qkv + 2 * (size_t)PART, attn);

    dim3 g3(M / 128, DM / 128);                     // 64 x 4
    gemm_k<1><<<g3, 256, 0, stream>>>(attn, wt_out, b_out, (float*)d_out, M, DM, DM);
}

// Round 9
// 151.119 us; speedup vs baseline: 1.6589x; 1.2044x over previous
//
#include <hip/hip_runtime.h>
#include <hip/hip_bf16.h>

#define BATCH 4
#define SEQ   2048
#define DM    512
#define NH    8
#define HD    64
#define PART  (BATCH*NH*SEQ*HD)   /* 4,194,304 = M*DM */
#define QSCALE 0.18033688f        /* (1/sqrt(64)) * log2(e) : folded into Q */

typedef unsigned short u16;
typedef unsigned int   u32;
typedef __bf16 bf16x8 __attribute__((ext_vector_type(8)));
typedef float  f32x4  __attribute__((ext_vector_type(4)));

__device__ __forceinline__ u16 f2bf(float f) {
    union { float f; u32 u; } v; v.f = f;
    u32 r = v.u + 0x7fffu + ((v.u >> 16) & 1u);   // RNE
    return (u16)(r >> 16);
}

// async global->LDS, 16B per lane; LDS dest = uniform base + lane*16
__device__ __forceinline__ void glds16(const u16* g, u16* lds) {
    __builtin_amdgcn_global_load_lds(
        (const __attribute__((address_space(1))) void*)g,
        (__attribute__((address_space(3))) void*)lds, 16, 0, 0);
}

// ---------------------------------------------------------------------------
// prep: z=0 -> f32->bf16 convert of x (512 blocks, grid-stride)
//       z=1 -> transpose w_qkv (192 blocks)   z=2 -> transpose w_out (64)
// ---------------------------------------------------------------------------
__global__ __launch_bounds__(256) void prep_k(
    const float* __restrict__ x, u16* __restrict__ xb,
    const float* __restrict__ w_qkv, u16* __restrict__ t_qkv,
    const float* __restrict__ w_out, u16* __restrict__ t_out)
{
    __shared__ u16 Ts[64][72];
    const int z = blockIdx.z, bx = blockIdx.x, t = threadIdx.x;

    if (z == 0) {
        const int n8 = PART / 8;
        for (int i = bx * 256 + t; i < n8; i += 512 * 256) {
            float4 a = *(const float4*)(x + (size_t)i * 8);
            float4 b = *(const float4*)(x + (size_t)i * 8 + 4);
            union { uint4 v; u16 s[8]; } o;
            o.s[0] = f2bf(a.x); o.s[1] = f2bf(a.y);
            o.s[2] = f2bf(a.z); o.s[3] = f2bf(a.w);
            o.s[4] = f2bf(b.x); o.s[5] = f2bf(b.y);
            o.s[6] = f2bf(b.z); o.s[7] = f2bf(b.w);
            *(uint4*)(xb + (size_t)i * 8) = o.v;
        }
        return;
    }
    const int N = (z == 1) ? 3 * DM : DM;
    const int ntiles = N / 64;
    if (bx >= ntiles * 8) return;
    const float* W = (z == 1) ? w_qkv : w_out;
    u16* Wt = (z == 1) ? t_qkv : t_out;
    const int n0 = (bx % ntiles) * 64, k0 = (bx / ntiles) * 64;

    #pragma unroll
    for (int l = 0; l < 4; ++l) {
        int idx = l * 1024 + t * 4;
        int r = idx >> 6, c = idx & 63;
        float4 v = *(const float4*)(W + (size_t)(k0 + r) * N + n0 + c);
        Ts[c + 0][r] = f2bf(v.x);
        Ts[c + 1][r] = f2bf(v.y);
        Ts[c + 2][r] = f2bf(v.z);
        Ts[c + 3][r] = f2bf(v.w);
    }
    __syncthreads();
    #pragma unroll
    for (int l = 0; l < 2; ++l) {
        int idx = l * 256 + t;
        int row = idx >> 3, ch = idx & 7;
        *(uint4*)(Wt + (size_t)(n0 + row) * DM + k0 + ch * 8) =
            *(const uint4*)(&Ts[row][ch * 8]);
    }
}

// ---------------------------------------------------------------------------
// GEMM: C(M,N) = A(M,K)bf16 @ Bt(N,K)^T bf16 + bias(N)f32.
// Double-buffered LDS, one barrier per K-step.
// MODE 0: BM=128; scatter into ws: Q (prescaled) | K (B,H,S,HD); V^T (B,H,HD,S).
// MODE 1: BM=64 (grid 128x4 = 512 blocks, 2/CU); row-major f32 store.
// ---------------------------------------------------------------------------
template<int MODE>
__global__ __launch_bounds__(256) void gemm_k(
    const u16* __restrict__ A, const u16* __restrict__ Bt,
    const float* __restrict__ bias, void* __restrict__ outv,
    int M, int N, int K)
{
    constexpr int BM = (MODE == 1) ? 64 : 128;
    constexpr int NI = (MODE == 1) ? 2 : 4;

    __shared__ __align__(16) u16 As[2][BM * 32];
    __shared__ __align__(16) u16 Bs[2][128 * 32];

    const int tid  = threadIdx.x;
    const int bm0  = blockIdx.x * BM;
    const int bn0  = blockIdx.y * 128;
    const int wave = tid >> 6, lane = tid & 63;
    const int l16  = lane & 15, quad = lane >> 4;
    const int wr   = (MODE == 1) ? 0 : (wave & 1) * 64;
    const int wc   = (MODE == 1) ? wave * 32 : (wave >> 1) * 64;

    const int srow = (lane >> 2);            // 0..15
    const int scol = (lane & 3) * 8;         // 0,8,16,24
    const int arow = (MODE == 1) ? (wave * 16) : (wave * 32);
    const u16* Ag = A + (size_t)(bm0 + arow + srow) * K + scol;
    const u16* Bg = Bt + (size_t)(bn0 + wave * 32 + srow) * K + scol;
    const int wofsA = arow * 32;
    const int wofsB = (wave * 32) * 32;

    f32x4 acc[4][NI];
    #pragma unroll
    for (int i = 0; i < 4; ++i)
        #pragma unroll
        for (int j = 0; j < NI; ++j)
            acc[i][j] = (f32x4){0.f, 0.f, 0.f, 0.f};

    glds16(Ag, &As[0][wofsA]);
    if (MODE == 0) glds16(Ag + (size_t)16 * K, &As[0][wofsA + 16 * 32]);
    glds16(Bg,                  &Bs[0][wofsB]);
    glds16(Bg + (size_t)16 * K, &Bs[0][wofsB + 16 * 32]);
    __syncthreads();

    const int NIT = K >> 5;
    for (int it = 0; it < NIT; ++it) {
        const int cur = it & 1;
        if (it + 1 < NIT) {
            const int nx = cur ^ 1;
            const int k0 = (it + 1) << 5;
            glds16(Ag + k0, &As[nx][wofsA]);
            if (MODE == 0) glds16(Ag + k0 + (size_t)16 * K, &As[nx][wofsA + 16 * 32]);
            glds16(Bg + k0,                  &Bs[nx][wofsB]);
            glds16(Bg + k0 + (size_t)16 * K, &Bs[nx][wofsB + 16 * 32]);
        }

        bf16x8 af[4], bfr[NI];
        #pragma unroll
        for (int mi = 0; mi < 4; ++mi)
            af[mi] = *(const bf16x8*)(&As[cur][(wr + mi * 16 + l16) * 32 + quad * 8]);
        #pragma unroll
        for (int ni = 0; ni < NI; ++ni)
            bfr[ni] = *(const bf16x8*)(&Bs[cur][(wc + ni * 16 + l16) * 32 + quad * 8]);
        #pragma unroll
        for (int mi = 0; mi < 4; ++mi)
            #pragma unroll
            for (int ni = 0; ni < NI; ++ni)
                acc[mi][ni] = __builtin_amdgcn_mfma_f32_16x16x32_bf16(
                    af[mi], bfr[ni], acc[mi][ni], 0, 0, 0);
        __syncthreads();
    }

    #pragma unroll
    for (int mi = 0; mi < 4; ++mi) {
        #pragma unroll
        for (int ni = 0; ni < NI; ++ni) {
            int col = bn0 + wc + ni * 16 + l16;
            float bv = bias[col];
            int row0 = bm0 + wr + mi * 16 + quad * 4;
            float v[4];
            #pragma unroll
            for (int reg = 0; reg < 4; ++reg) v[reg] = acc[mi][ni][reg] + bv;

            if (MODE == 1) {
                #pragma unroll
                for (int reg = 0; reg < 4; ++reg)
                    ((float*)outv)[(size_t)(row0 + reg) * N + col] = v[reg];
            } else {
                u16* ws = (u16*)outv;
                int part = col >> 9, wi = col & 511;
                int h = wi >> 6, e = wi & 63;
                int b = row0 >> 11, s0 = row0 & 2047;
                if (part == 2) {
                    union { u16 q[4]; uint2 u; } pk;
                    #pragma unroll
                    for (int reg = 0; reg < 4; ++reg) pk.q[reg] = f2bf(v[reg]);
                    *(uint2*)(ws + (size_t)2 * PART +
                              ((size_t)(b * NH + h) * HD + e) * SEQ + s0) = pk.u;
                } else {
                    float scl = (part == 0) ? QSCALE : 1.0f;
                    #pragma unroll
                    for (int reg = 0; reg < 4; ++reg)
                        ws[(size_t)part * PART +
                           ((size_t)(b * NH + h) * SEQ + s0 + reg) * HD + e] =
                            f2bf(v[reg] * scl);
                }
            }
        }
    }
}

// ---------------------------------------------------------------------------
// Causal flash attention, streaming softmax (exp2; scale folded into Q).
// Q,K: (B,H,S,HD) bf16. Vt: (B,H,HD,S) bf16. Out: (B,S,H,HD) bf16.
// UNIFORM-WORK blocks: each block processes q-tile PAIR (31-pair, pair) of
// 64 rows each, sequentially -> every block runs exactly 33 k-tile
// iterations (no LPT tail: 8 waves stay resident on every CU to the end).
// Inner loop = round-6 structure: K/V glds16 into double-buffered
// XOR-chunk-swizzled LDS, ONE barrier per k-tile, P wave-private in Ps.
// Grid x=bh keeps a bh's 16 blocks on one XCD (K/V L2-local).
// ---------------------------------------------------------------------------
__global__ __launch_bounds__(256) void attn_k(
    const u16* __restrict__ Q, const u16* __restrict__ K,
    const u16* __restrict__ Vt, u16* __restrict__ O)
{
    __shared__ __align__(16) u16 KsB[2][64 * 64];   // [kv][d], chunk-swizzled
    __shared__ __align__(16) u16 VtB[2][64 * 64];   // [d][kv], chunk-swizzled
    __shared__ __align__(16) u16 Ps[64][72];        // Q stage, then P (wave-priv)

    const int bh = blockIdx.x;
    const int pair = blockIdx.y;               // 0..15
    const int tid = threadIdx.x, wave = tid >> 6, lane = tid & 63;
    const int l16 = lane & 15, quad = lane >> 4;
    const size_t baseK = (size_t)bh * SEQ * HD;
    const size_t baseV = (size_t)bh * HD * SEQ;
    const int b = bh >> 3, h = bh & 7;
    const int row64 = wave * 16 + quad * 4;    // row-in-tile (reg adds 0..3)

    // glds lane source addressing (XOR chunk swizzle at the source)
    const int sub = lane >> 3;                 // 0..7
    const int lcx = (lane & 7) ^ sub;          // logical 16B chunk for this lane
    const u16* kg = K  + baseK + (size_t)((wave * 16 + sub) * 64)   + lcx * 8;
    const u16* vg = Vt + baseV + (size_t)((wave * 16 + sub) * 2048) + lcx * 8;
    u16* ksd = &KsB[0][wave * 1024];
    u16* vtd = &VtB[0][wave * 1024];

    #pragma unroll
    for (int phase = 0; phase < 2; ++phase) {
        const int qt = phase ? pair : (31 - pair);   // 33 iters total/block
        const size_t baseQ = baseK + (size_t)qt * 64 * HD;

        // ---- stage Q (64x64) into Ps ----
        #pragma unroll
        for (int r = 0; r < 2; ++r) {
            int chunk = r * 256 + tid;
            int row = chunk >> 3, c8 = (chunk & 7) << 3;
            *(uint4*)(&Ps[row][c8]) = *(const uint4*)(Q + baseQ + row * 64 + c8);
        }
        __syncthreads();
        bf16x8 qf[2];
        #pragma unroll
        for (int d0 = 0; d0 < 2; ++d0)
            qf[d0] = *(const bf16x8*)(&Ps[wave * 16 + l16][d0 * 32 + quad * 8]);
        __syncthreads();   // qf reads done before Ps is overwritten with P

        // prefetch kt=0 into buffer 0
        glds16(kg,            ksd);
        glds16(kg + 8 * 64,   ksd + 512);
        glds16(vg,            vtd);
        glds16(vg + 8 * 2048, vtd + 512);
        __syncthreads();   // vmcnt(0) drain: buf0 landed

        float l_part[4] = {0.f, 0.f, 0.f, 0.f};
        f32x4 o_acc[4];
        #pragma unroll
        for (int i = 0; i < 4; ++i) o_acc[i] = (f32x4){0.f, 0.f, 0.f, 0.f};

        for (int kt = 0; kt <= qt; ++kt) {
            const int cur = kt & 1;
            if (kt < qt) {
                const int nx = (cur ^ 1) * 4096;
                glds16(kg + (size_t)(kt + 1) * 4096,          ksd + nx);
                glds16(kg + (size_t)(kt + 1) * 4096 + 8 * 64, ksd + nx + 512);
                glds16(vg + (size_t)(kt + 1) * 64,            vtd + nx);
                glds16(vg + (size_t)(kt + 1) * 64 + 8 * 2048, vtd + nx + 512);
            }

            // K and V fragments up front (ds latency overlaps MFMA+exp)
            bf16x8 kf[2][4], vf[2][4];
            #pragma unroll
            for (int d0 = 0; d0 < 2; ++d0)
                #pragma unroll
                for (int nt = 0; nt < 4; ++nt) {
                    int pc = (d0 * 4 + quad) ^ (l16 & 7);
                    kf[d0][nt] = *(const bf16x8*)
                        (&KsB[cur][(nt * 16 + l16) * 64 + pc * 8]);
                    vf[d0][nt] = *(const bf16x8*)
                        (&VtB[cur][(nt * 16 + l16) * 64 + pc * 8]);
                }

            f32x4 s[4];
            #pragma unroll
            for (int nt = 0; nt < 4; ++nt) s[nt] = (f32x4){0.f, 0.f, 0.f, 0.f};
            #pragma unroll
            for (int d0 = 0; d0 < 2; ++d0)
                #pragma unroll
                for (int nt = 0; nt < 4; ++nt)
                    s[nt] = __builtin_amdgcn_mfma_f32_16x16x32_bf16(
                        qf[d0], kf[d0][nt], s[nt], 0, 0, 0);

            const bool diag = (kt == qt);
            #pragma unroll
            for (int nt = 0; nt < 4; ++nt) {
                int cl = nt * 16 + l16;
                float p[4];
                #pragma unroll
                for (int reg = 0; reg < 4; ++reg) {
                    p[reg] = __builtin_amdgcn_exp2f(s[nt][reg]);
                    if (diag && cl > row64 + reg) p[reg] = 0.f;
                    l_part[reg] += p[reg];
                }
                union { __hip_bfloat162 hh; u16 s2[2]; } pk01, pk23;
                pk01.hh = __float22bfloat162_rn(float2{p[0], p[1]});
                pk23.hh = __float22bfloat162_rn(float2{p[2], p[3]});
                Ps[row64 + 0][cl] = pk01.s2[0];
                Ps[row64 + 1][cl] = pk01.s2[1];
                Ps[row64 + 2][cl] = pk23.s2[0];
                Ps[row64 + 3][cl] = pk23.s2[1];
            }

            // PV: Ps rows wave-private; lgkmcnt orders write->read
            #pragma unroll
            for (int k0 = 0; k0 < 2; ++k0) {
                bf16x8 ap = *(const bf16x8*)
                    (&Ps[wave * 16 + l16][k0 * 32 + quad * 8]);
                #pragma unroll
                for (int dt = 0; dt < 4; ++dt)
                    o_acc[dt] = __builtin_amdgcn_mfma_f32_16x16x32_bf16(
                        ap, vf[k0][dt], o_acc[dt], 0, 0, 0);
            }
            __syncthreads();   // all waves done with buf[cur]; prefetch drained
        }

        // ---- reduce l across the 16 lanes sharing each q-row; store O ----
        float l_i[4];
        #pragma unroll
        for (int reg = 0; reg < 4; ++reg) {
            float l = l_part[reg];
            #pragma unroll
            for (int off = 1; off < 16; off <<= 1)
                l += __shfl_xor(l, off);
            l_i[reg] = l;
        }
        #pragma unroll
        for (int dt = 0; dt < 4; ++dt) {
            #pragma unroll
            for (int reg = 0; reg < 4; ++reg) {
                int srow = qt * 64 + row64 + reg;
                float v = o_acc[dt][reg] / l_i[reg];
                size_t idx = (((size_t)(b * SEQ + srow)) * NH + h) * HD
                             + dt * 16 + l16;
                O[idx] = f2bf(v);
            }
        }
    }
}

extern "C" void kernel_launch(void* const* d_in, const int* in_sizes, int n_in,
                              void* d_out, int out_size, void* d_ws, size_t ws_size,
                              hipStream_t stream) {
    const float* x     = (const float*)d_in[0];
    const float* w_qkv = (const float*)d_in[1];
    const float* b_qkv = (const float*)d_in[2];
    const float* w_out = (const float*)d_in[3];
    const float* b_out = (const float*)d_in[4];

    u16* qkv    = (u16*)d_ws;                       // Q | K | V^T, each PART
    u16* attn   = qkv + (size_t)3 * PART;           // PART bf16 (B,S,H,HD)
    u16* xb     = attn + (size_t)PART;              // PART bf16 (x converted)
    u16* wt_qkv = xb + (size_t)PART;                // 1536*512 bf16
    u16* wt_out = wt_qkv + (size_t)(3 * DM) * DM;   // 512*512 bf16

    const int M = BATCH * SEQ;                      // 8192

    prep_k<<<dim3(512, 1, 3), 256, 0, stream>>>(x, xb, w_qkv, wt_qkv,
                                                w_out, wt_out);

    dim3 g1(M / 128, (3 * DM) / 128);               // 64 x 12
    gemm_k<0><<<g1, 256, 0, stream>>>(xb, wt_qkv, b_qkv, qkv, M, 3 * DM, DM);

    dim3 g2(BATCH * NH, 16);                        // bh x pair (uniform work)
    attn_k<<<g2, 256, 0, stream>>>(qkv, qkv + PART, qkv + 2 * (size_t)PART, attn);

    dim3 g3(M / 64, DM / 128);                      // 128 x 4 = 512 blocks
    gemm_k<1><<<g3, 256, 0, stream>>>(attn, wt_out, b_out, (float*)d_out, M, DM, DM);
}